// Round 9
// baseline (343.203 us; speedup 1.0000x reference)
//
#include <hip/hip_runtime.h>
#include <math.h>

typedef __attribute__((ext_vector_type(8))) short short8;
typedef __attribute__((ext_vector_type(16))) float floatx16;

#define NSV 8192
#define MSV 8192
#define CF 96
#define NCLS 20

#define C48 48.08983469629878f     // 1/(0.03*ln2)
#define C96 96.17966939259756f     // 2*C48
#define CEV -2.885390081777927f    // -2/ln2

// ---- workspace byte offsets ----
// A/B splits stored FRAGMENT-PACKED: within split s, byte offset
//   ((g*6 + kc) << 10) + lane*16,  g = rowgroup (32 rows), kc = k-chunk (16 k),
//   lane = (k_half<<5) | (row&31); each 16B = 8 bf16 of one row's k-half.
#define OFF_A0    0u
#define OFF_A1    1572864u
#define OFF_A2    3145728u
#define OFF_B0    4718592u
#define OFF_B1    6291456u
#define OFF_B2    7864320u
#define OFF_RV4   9437184u   // float4[8192]: x = 1/|a| (prep) then b_i (bvec); yzw = ori
#define OFF_CV4   9568256u   // float4[8192]: x = 1/|b|; yzw = al_sur
#define OFF_PROW  9699328u   // float[8192*64] partial row sums
#define OFF_SMENC 11796480u  // u64[8192]
#define OFF_SMIDX 11862016u
#define OFF_WIN   11894784u
#define OFF_CONF  11927552u
#define OFF_FLAG  11960320u

// ---- output float offsets ----
#define O_TRUST 0
#define O_PROB  NSV
#define O_PRE   (O_PROB + NSV*NCLS)
#define O_SM    (O_PRE + NSV)

__device__ __forceinline__ unsigned short bfr(float x) {
  unsigned u = __float_as_uint(x);
  return (unsigned short)((u + 0x7FFFu + ((u >> 16) & 1u)) >> 16);
}
__device__ __forceinline__ float bff(unsigned short h) {
  return __uint_as_float(((unsigned)h) << 16);
}
__device__ __forceinline__ float fexp2(float x) {
  float r; asm("v_exp_f32 %0, %1" : "=v"(r) : "v"(x)); return r;
}

// 4x4 inverse (fp64 Gauss-Jordan) + norms, coord transform, packed structs
__global__ void k_prep(const float* __restrict__ surf, const float* __restrict__ surc,
                       const float* __restrict__ meanf, const float* __restrict__ ori,
                       const float* __restrict__ posses, char* __restrict__ wsb) {
  __shared__ float dsh[12];
  if (threadIdx.x == 0) {
    double m[4][8];
    for (int r = 0; r < 4; ++r)
      for (int c = 0; c < 4; ++c) { m[r][c] = (double)posses[16 + r*4 + c]; m[r][4+c] = (r == c) ? 1.0 : 0.0; }
    for (int col = 0; col < 4; ++col) {
      int piv = col; double best = fabs(m[col][col]);
      for (int r = col+1; r < 4; ++r) { double v = fabs(m[r][col]); if (v > best) { best = v; piv = r; } }
      if (piv != col) for (int c = 0; c < 8; ++c) { double tt = m[col][c]; m[col][c] = m[piv][c]; m[piv][c] = tt; }
      double pv = m[col][col];
      for (int c = 0; c < 8; ++c) m[col][c] /= pv;
      for (int r = 0; r < 4; ++r) if (r != col) {
        double f = m[r][col];
        for (int c = 0; c < 8; ++c) m[r][c] -= f * m[col][c];
      }
    }
    for (int r = 0; r < 3; ++r)
      for (int c = 0; c < 4; ++c) {
        double s = 0.0;
        for (int k = 0; k < 4; ++k) s += m[r][4+k] * (double)posses[k*4 + c];
        dsh[r*4 + c] = (float)s;
      }
  }
  __syncthreads();
  int j = blockIdx.x*256 + threadIdx.x;
  if (j >= NSV) return;
  float d[12];
  #pragma unroll
  for (int q = 0; q < 12; ++q) d[q] = dsh[q];
  float x = surc[j*3+0], y = surc[j*3+1], z = surc[j*3+2];
  float ax = ((x*d[0] + y*d[1]) + z*d[2]) + d[3];
  float ay = ((x*d[4] + y*d[5]) + z*d[6]) + d[7];
  float az = ((x*d[8] + y*d[9]) + z*d[10]) + d[11];
  const float4* f2 = (const float4*)(surf  + (size_t)j*CF);
  const float4* f1 = (const float4*)(meanf + (size_t)j*CF);
  float s2 = 0.f, s1 = 0.f;
  #pragma unroll
  for (int kq = 0; kq < 24; ++kq) {
    float4 v = f2[kq]; s2 += v.x*v.x; s2 += v.y*v.y; s2 += v.z*v.z; s2 += v.w*v.w;
  }
  #pragma unroll
  for (int kq = 0; kq < 24; ++kq) {
    float4 v = f1[kq]; s1 += v.x*v.x; s1 += v.y*v.y; s1 += v.z*v.z; s1 += v.w*v.w;
  }
  float4 cvv; cvv.x = 1.0f/sqrtf(s2); cvv.y = ax; cvv.z = ay; cvv.w = az;
  ((float4*)(wsb + OFF_CV4))[j] = cvv;
  float4 rvv; rvv.x = 1.0f/sqrtf(s1); rvv.y = ori[j*3+0]; rvv.z = ori[j*3+1]; rvv.w = ori[j*3+2];
  ((float4*)(wsb + OFF_RV4))[j] = rvv;
}

// 3-way bf16 split of PRE-SCALED features (A x 48.09/|a|, B x 1/|b|),
// written in MFMA-fragment-packed order (see layout comment above).
__global__ void k_split(const float* __restrict__ meanf, const float* __restrict__ surf,
                        char* __restrict__ wsb) {
  const int NT = NSV*CF/4;
  int idx = blockIdx.x*256 + threadIdx.x;
  if (idx >= 2*NT) return;
  int m = idx >= NT;
  int e4 = idx - (m ? NT : 0);
  int base4 = e4 * 4;
  int row = base4 / CF;
  int k0  = base4 - row*CF;          // 0,4,...,92
  const float* src = m ? surf : meanf;
  float scale;
  if (m) scale = ((const float4*)(wsb + OFF_CV4))[row].x;
  else   scale = ((const float4*)(wsb + OFF_RV4))[row].x * C48;
  unsigned short* d0 = (unsigned short*)(wsb + (m ? OFF_B0 : OFF_A0));
  unsigned short* d1 = (unsigned short*)(wsb + (m ? OFF_B1 : OFF_A1));
  unsigned short* d2 = (unsigned short*)(wsb + (m ? OFF_B2 : OFF_A2));
  float4 v = *(const float4*)(src + base4);
  float xs[4] = {v.x*scale, v.y*scale, v.z*scale, v.w*scale};
  unsigned short h0[4], h1[4], h2[4];
  #pragma unroll
  for (int c = 0; c < 4; ++c) {
    float x = xs[c];
    unsigned short a0 = bfr(x);  float r1 = x - bff(a0);
    unsigned short a1 = bfr(r1); float r2 = r1 - bff(a1);
    h0[c] = a0; h1[c] = a1; h2[c] = bfr(r2);
  }
  // fragment-packed destination (in ushort units):
  int g   = row >> 5;
  int l31 = row & 31;
  int kc  = k0 >> 4;
  int hi  = (k0 >> 3) & 1;
  int e8  = k0 & 7;                  // 0 or 4
  int offu = ((g*6 + kc) << 9) + (((hi << 5) | l31) << 3) + e8;
  *(ushort4*)(d0 + offu) = make_ushort4(h0[0], h0[1], h0[2], h0[3]);
  *(ushort4*)(d1 + offu) = make_ushort4(h1[0], h1[1], h1[2], h1[3]);
  *(ushort4*)(d2 + offu) = make_ushort4(h2[0], h2[1], h2[2], h2[3]);
}

// Heavy GEMM pass: 128x128 tile, 4 waves (2x2), wave tile 64x64 via 2x2 mfma_32x32x16_bf16.
// LDS-staged in TWO K=48 half-tiles (72 KB, 18x global_load_lds w16 per half),
// only 3 barriers per block; fragments then ds_read_b128 (contiguous, conflict-free).
// Halves the L2 traffic vs register-direct (fragments shared across waves via LDS)
// and replaces exposed L2 latency (~300cy) with ds_read latency (~120cy).
// PASS 1: rowsums.  PASS 2: per-column argmax of K*b.
template<int PASS>
__global__ __launch_bounds__(256, 2)
void k_gemm(char* __restrict__ wsb) {
  const float4* RV  = (const float4*)(wsb + OFF_RV4);
  const float4* CVC = (const float4*)(wsb + OFF_CV4);
  float* PROW = (float*)(wsb + OFF_PROW);
  unsigned long long* SME = (unsigned long long*)(wsb + OFF_SMENC);

  __shared__ char lds[73728];                   // 72 pages x 1 KB (page = 32 rows x 16 k)
  __shared__ unsigned long long redbuf[2][128];

  int t = threadIdx.x, lane = t & 63, wid = t >> 6;
  int wr = wid >> 1, wc = wid & 1, l31 = lane & 31, hi = lane >> 5;
  // 2D XCD chunking: XCD (xr,xc) owns 16 bi x 32 bj -> L2-resident panels
  int flat = blockIdx.y*64 + blockIdx.x;
  int xcd = flat & 7, q = flat >> 3;
  int xr = xcd >> 1, xc = xcd & 1;
  int bi = xr*16 + (q & 15), bj = xc*32 + (q >> 4);
  int I0 = bi*128, J0 = bj*128;

  const unsigned offsA[3] = {OFF_A0, OFF_A1, OFF_A2};
  const unsigned offsB[3] = {OFF_B0, OFF_B1, OFF_B2};

  // stage one K=48 half (h = 0 or 1): 72 pages, 4 pages (one per wave) per call.
  // page p: side = p>=36 (A/B), s = split, gl = local rowgroup, c = local k-chunk.
  auto stage = [&](int h) {
    #pragma unroll
    for (int qq = 0; qq < 18; ++qq) {
      int p = qq*4 + wid;
      int side = (p >= 36) ? 1 : 0;
      int r = p - side*36;
      int s = r / 12;
      int rem = r - s*12;
      int gl = rem / 3;
      int c = rem - gl*3;
      unsigned base = side ? offsB[s] : offsA[s];
      int g = ((side ? J0 : I0) >> 5) + gl;
      const char* gp = wsb + base + (((unsigned)(g*6 + h*3 + c)) << 10) + lane*16;
      char* lp = lds + p*1024 + lane*16;
      __builtin_amdgcn_global_load_lds((const __attribute__((address_space(1))) void*)gp,
                                       (__attribute__((address_space(3))) void*)lp, 16, 0, 0);
    }
  };

  floatx16 acc[2][2];
  #pragma unroll
  for (int ti = 0; ti < 2; ++ti)
    #pragma unroll
    for (int tj = 0; tj < 2; ++tj)
      #pragma unroll
      for (int e = 0; e < 16; ++e) acc[ti][tj][e] = 0.f;

  auto compute_half = [&]() {
    #pragma unroll
    for (int c = 0; c < 3; ++c) {
      short8 fa[3][2], fb[3][2];
      #pragma unroll
      for (int s = 0; s < 3; ++s)
        #pragma unroll
        for (int ti = 0; ti < 2; ++ti) {
          int pa = s*12 + (wr*2 + ti)*3 + c;
          fa[s][ti] = *(const short8*)(lds + pa*1024 + lane*16);
          int pb = 36 + s*12 + (wc*2 + ti)*3 + c;
          fb[s][ti] = *(const short8*)(lds + pb*1024 + lane*16);
        }
      #pragma unroll
      for (int ti = 0; ti < 2; ++ti)
        #pragma unroll
        for (int tj = 0; tj < 2; ++tj) {
          acc[ti][tj] = __builtin_amdgcn_mfma_f32_32x32x16_bf16(fa[0][ti], fb[0][tj], acc[ti][tj], 0, 0, 0);
          acc[ti][tj] = __builtin_amdgcn_mfma_f32_32x32x16_bf16(fa[0][ti], fb[1][tj], acc[ti][tj], 0, 0, 0);
          acc[ti][tj] = __builtin_amdgcn_mfma_f32_32x32x16_bf16(fa[1][ti], fb[0][tj], acc[ti][tj], 0, 0, 0);
          acc[ti][tj] = __builtin_amdgcn_mfma_f32_32x32x16_bf16(fa[1][ti], fb[1][tj], acc[ti][tj], 0, 0, 0);
          acc[ti][tj] = __builtin_amdgcn_mfma_f32_32x32x16_bf16(fa[0][ti], fb[2][tj], acc[ti][tj], 0, 0, 0);
          acc[ti][tj] = __builtin_amdgcn_mfma_f32_32x32x16_bf16(fa[2][ti], fb[0][tj], acc[ti][tj], 0, 0, 0);
        }
    }
  };

  stage(0);
  __syncthreads();        // drains vmcnt(0): half 0 visible
  compute_half();
  __syncthreads();        // all waves done reading buffer before overwrite
  stage(1);
  __syncthreads();        // half 1 visible
  compute_half();

  // ---- epilogue ----
  float4 cv[2];
  #pragma unroll
  for (int tj = 0; tj < 2; ++tj) cv[tj] = CVC[J0 + wc*64 + tj*32 + l31];

  if (PASS == 1) {
    float* rowred = (float*)redbuf;   // [2][128] floats
    #pragma unroll
    for (int ti = 0; ti < 2; ++ti) {
      #pragma unroll
      for (int r = 0; r < 16; ++r) {
        int lr = wr*64 + ti*32 + (r & 3) + 8*(r >> 2) + 4*hi;
        int row = I0 + lr;
        float4 rv = RV[row];
        float rowp = 0.f;
        #pragma unroll
        for (int tj = 0; tj < 2; ++tj) {
          float dotv = acc[ti][tj][r];                  // = 48.09 * cos
          float dx = rv.y - cv[tj].y, dy = rv.z - cv[tj].z, dz = rv.w - cv[tj].w;
          float s3 = fmaf(dz, dz, fmaf(dy, dy, dx*dx));
          float ev = fexp2(s3 * CEV);                   // exp(-2*s3)
          float kv = fexp2(fmaf(ev, C48, dotv - C96));
          kv = (s3 < 25.0f) ? kv : 0.0f;
          rowp += kv;
        }
        rowp += __shfl_xor(rowp, 1);
        rowp += __shfl_xor(rowp, 2);
        rowp += __shfl_xor(rowp, 4);
        rowp += __shfl_xor(rowp, 8);
        rowp += __shfl_xor(rowp, 16);
        if (l31 == 0) rowred[wc*128 + lr] = rowp;
      }
    }
    __syncthreads();
    if (t < 128) PROW[(size_t)(I0 + t)*64 + bj] = rowred[t] + rowred[128 + t];
  } else {
    unsigned long long benc[2] = {0ull, 0ull};
    #pragma unroll
    for (int ti = 0; ti < 2; ++ti) {
      #pragma unroll
      for (int r = 0; r < 16; ++r) {
        int lr = wr*64 + ti*32 + (r & 3) + 8*(r >> 2) + 4*hi;
        int row = I0 + lr;
        float4 rv = RV[row];                            // rv.x = b_i
        unsigned rinv = 0xFFFFFFFFu - (unsigned)row;
        #pragma unroll
        for (int tj = 0; tj < 2; ++tj) {
          float dotv = acc[ti][tj][r];
          float dx = rv.y - cv[tj].y, dy = rv.z - cv[tj].z, dz = rv.w - cv[tj].w;
          float s3 = fmaf(dz, dz, fmaf(dy, dy, dx*dx));
          float ev = fexp2(s3 * CEV);
          float kv = fexp2(fmaf(ev, C48, dotv - C96));
          kv = (s3 < 25.0f) ? kv : 0.0f;
          float val = kv * rv.x;
          unsigned long long e = ((unsigned long long)__float_as_uint(val) << 32)
                               | (unsigned long long)rinv;
          benc[tj] = (e > benc[tj]) ? e : benc[tj];
        }
      }
    }
    #pragma unroll
    for (int tj = 0; tj < 2; ++tj) {
      unsigned long long o = __shfl_xor(benc[tj], 32);
      if (o > benc[tj]) benc[tj] = o;
      if (hi == 0) redbuf[wr][wc*64 + tj*32 + l31] = benc[tj];
    }
    __syncthreads();
    if (t < 128) {
      unsigned long long e0 = redbuf[0][t], e1 = redbuf[1][t];
      atomicMax(SME + (J0 + t), e0 > e1 ? e0 : e1);
    }
  }
}

// reduce partials -> b_i into RV4.x; init winner/flag/smenc
__global__ void k_bvec(char* __restrict__ wsb) {
  int i = blockIdx.x*256 + threadIdx.x;
  if (i >= NSV) return;
  const float* p = (const float*)(wsb + OFF_PROW) + (size_t)i*64;
  float s = 0.f;
  #pragma unroll
  for (int q = 0; q < 64; ++q) s += p[q];
  float b = 0x1p-13f / (s * 0x1p-13f + 1e-16f);
  ((float*)(wsb + OFF_RV4))[(size_t)i*4] = b;
  ((int*)(wsb + OFF_WIN))[i] = -1;
  ((unsigned long long*)(wsb + OFF_SMENC))[i] = 0ull;
  if (i == 0) *((int*)(wsb + OFF_FLAG)) = 0;
}

__global__ void k_softmax(const float* __restrict__ svp, float* __restrict__ out) {
  int i = blockIdx.x*256 + threadIdx.x;
  if (i >= NSV) return;
  const float* x = svp + (size_t)i*NCLS;
  float mx = x[0];
  for (int c = 1; c < NCLS; ++c) mx = fmaxf(mx, x[c]);
  float e[NCLS]; float s = 0.f;
  for (int c = 0; c < NCLS; ++c) { e[c] = expf(x[c] - mx); s += e[c]; }
  float* p = out + O_PROB + (size_t)i*NCLS;
  for (int c = 0; c < NCLS; ++c) p[c] = e[c]/s;
}

__global__ void k_conf(const int* __restrict__ gt, char* __restrict__ wsb, float* __restrict__ out) {
  int j = blockIdx.x*256 + threadIdx.x;
  if (j >= MSV) return;
  unsigned long long enc = ((const unsigned long long*)(wsb + OFF_SMENC))[j];
  int sm = (int)(0xFFFFFFFFu - (unsigned)(enc & 0xFFFFFFFFull));
  ((int*)(wsb + OFF_SMIDX))[j] = sm;
  out[O_SM + j] = (float)sm;
  float c = out[O_PROB + (size_t)sm*NCLS + gt[j]];
  ((float*)(wsb + OFF_CONF))[j] = c;
  unsigned long long m = __ballot(c > 0.1f);
  if ((threadIdx.x & 63) == 0 && m) atomicOr((int*)(wsb + OFF_FLAG), 1);
}

__global__ void k_winner(char* __restrict__ wsb) {
  int j = blockIdx.x*256 + threadIdx.x;
  if (j >= MSV) return;
  float c = ((const float*)(wsb + OFF_CONF))[j];
  int f = *((const int*)(wsb + OFF_FLAG));
  bool tm = f ? (c > 0.1f) : (c > 0.0f);
  if (tm) atomicMax(((int*)(wsb + OFF_WIN)) + ((const int*)(wsb + OFF_SMIDX))[j], j);
}

__global__ void k_final(const int* __restrict__ gt, float* __restrict__ out, const char* __restrict__ wsb) {
  int i = blockIdx.x*256 + threadIdx.x;
  if (i >= NSV) return;
  int w = ((const int*)(wsb + OFF_WIN))[i];
  float* row = out + O_PROB + (size_t)i*NCLS;
  if (w >= 0) {
    int g = gt[w];
    for (int c = 0; c < NCLS; ++c) row[c] = (c == g) ? 1.f : 0.f;
  }
  out[O_TRUST + i] = (w >= 0) ? 1.f : 0.f;
  float mx = row[0]; int pi = 0;
  for (int c = 1; c < NCLS; ++c) { float v = row[c]; if (v > mx) { mx = v; pi = c; } }
  out[O_PRE + i] = (float)pi;
}

extern "C" void kernel_launch(void* const* d_in, const int* in_sizes, int n_in,
                              void* d_out, int out_size, void* d_ws, size_t ws_size,
                              hipStream_t stream) {
  const float* surf  = (const float*)d_in[0];
  const float* surc  = (const float*)d_in[1];
  const int*   gt    = (const int*)d_in[2];
  const float* svp   = (const float*)d_in[3];
  const float* meanf = (const float*)d_in[4];
  const float* ori   = (const float*)d_in[5];
  const float* poss  = (const float*)d_in[6];
  float* out = (float*)d_out;
  char* wsb = (char*)d_ws;

  k_prep<<<NSV/256, 256, 0, stream>>>(surf, surc, meanf, ori, poss, wsb);
  k_split<<<1536, 256, 0, stream>>>(meanf, surf, wsb);
  k_gemm<1><<<dim3(64, 64), 256, 0, stream>>>(wsb);
  k_bvec<<<NSV/256, 256, 0, stream>>>(wsb);
  k_gemm<2><<<dim3(64, 64), 256, 0, stream>>>(wsb);
  k_softmax<<<NSV/256, 256, 0, stream>>>(svp, out);
  k_conf<<<MSV/256, 256, 0, stream>>>(gt, wsb, out);
  k_winner<<<MSV/256, 256, 0, stream>>>(wsb);
  k_final<<<NSV/256, 256, 0, stream>>>(gt, out, wsb);
}

// Round 10
// 332.201 us; speedup vs baseline: 1.0331x; 1.0331x over previous
//
#include <hip/hip_runtime.h>
#include <math.h>

typedef __attribute__((ext_vector_type(8))) short short8;
typedef __attribute__((ext_vector_type(16))) float floatx16;

#define NSV 8192
#define MSV 8192
#define CF 96
#define NCLS 20

#define C48 48.08983469629878f     // 1/(0.03*ln2)
#define C96 96.17966939259756f     // 2*C48
#define CEV -2.885390081777927f    // -2/ln2

// ---- workspace byte offsets ----
// A/B splits stored FRAGMENT-PACKED: within split s, byte offset
//   ((g*6 + kc) << 10) + lane*16,  g = rowgroup (32 rows), kc = k-chunk (16 k),
//   lane = (k_half<<5) | (row&31); each 16B = 8 bf16 of one row's k-half.
#define OFF_A0    0u
#define OFF_A1    1572864u
#define OFF_A2    3145728u
#define OFF_B0    4718592u
#define OFF_B1    6291456u
#define OFF_B2    7864320u
#define OFF_RV4   9437184u   // float4[8192]: x = 1/|a| (prep) then b_i (bvec); yzw = ori
#define OFF_CV4   9568256u   // float4[8192]: x = 1/|b|; yzw = al_sur
#define OFF_PROW  9699328u   // float[8192*64] partial row sums
#define OFF_SMENC 11796480u  // u64[8192]
#define OFF_SMIDX 11862016u
#define OFF_WIN   11894784u
#define OFF_CONF  11927552u
#define OFF_FLAG  11960320u

// ---- output float offsets ----
#define O_TRUST 0
#define O_PROB  NSV
#define O_PRE   (O_PROB + NSV*NCLS)
#define O_SM    (O_PRE + NSV)

__device__ __forceinline__ unsigned short bfr(float x) {
  unsigned u = __float_as_uint(x);
  return (unsigned short)((u + 0x7FFFu + ((u >> 16) & 1u)) >> 16);
}
__device__ __forceinline__ float bff(unsigned short h) {
  return __uint_as_float(((unsigned)h) << 16);
}
__device__ __forceinline__ float fexp2(float x) {
  float r; asm("v_exp_f32 %0, %1" : "=v"(r) : "v"(x)); return r;
}

// 4x4 inverse (fp64 Gauss-Jordan) + norms, coord transform, packed structs
__global__ void k_prep(const float* __restrict__ surf, const float* __restrict__ surc,
                       const float* __restrict__ meanf, const float* __restrict__ ori,
                       const float* __restrict__ posses, char* __restrict__ wsb) {
  __shared__ float dsh[12];
  if (threadIdx.x == 0) {
    double m[4][8];
    for (int r = 0; r < 4; ++r)
      for (int c = 0; c < 4; ++c) { m[r][c] = (double)posses[16 + r*4 + c]; m[r][4+c] = (r == c) ? 1.0 : 0.0; }
    for (int col = 0; col < 4; ++col) {
      int piv = col; double best = fabs(m[col][col]);
      for (int r = col+1; r < 4; ++r) { double v = fabs(m[r][col]); if (v > best) { best = v; piv = r; } }
      if (piv != col) for (int c = 0; c < 8; ++c) { double tt = m[col][c]; m[col][c] = m[piv][c]; m[piv][c] = tt; }
      double pv = m[col][col];
      for (int c = 0; c < 8; ++c) m[col][c] /= pv;
      for (int r = 0; r < 4; ++r) if (r != col) {
        double f = m[r][col];
        for (int c = 0; c < 8; ++c) m[r][c] -= f * m[col][c];
      }
    }
    for (int r = 0; r < 3; ++r)
      for (int c = 0; c < 4; ++c) {
        double s = 0.0;
        for (int k = 0; k < 4; ++k) s += m[r][4+k] * (double)posses[k*4 + c];
        dsh[r*4 + c] = (float)s;
      }
  }
  __syncthreads();
  int j = blockIdx.x*256 + threadIdx.x;
  if (j >= NSV) return;
  float d[12];
  #pragma unroll
  for (int q = 0; q < 12; ++q) d[q] = dsh[q];
  float x = surc[j*3+0], y = surc[j*3+1], z = surc[j*3+2];
  float ax = ((x*d[0] + y*d[1]) + z*d[2]) + d[3];
  float ay = ((x*d[4] + y*d[5]) + z*d[6]) + d[7];
  float az = ((x*d[8] + y*d[9]) + z*d[10]) + d[11];
  const float4* f2 = (const float4*)(surf  + (size_t)j*CF);
  const float4* f1 = (const float4*)(meanf + (size_t)j*CF);
  float s2 = 0.f, s1 = 0.f;
  #pragma unroll
  for (int kq = 0; kq < 24; ++kq) {
    float4 v = f2[kq]; s2 += v.x*v.x; s2 += v.y*v.y; s2 += v.z*v.z; s2 += v.w*v.w;
  }
  #pragma unroll
  for (int kq = 0; kq < 24; ++kq) {
    float4 v = f1[kq]; s1 += v.x*v.x; s1 += v.y*v.y; s1 += v.z*v.z; s1 += v.w*v.w;
  }
  float4 cvv; cvv.x = 1.0f/sqrtf(s2); cvv.y = ax; cvv.z = ay; cvv.w = az;
  ((float4*)(wsb + OFF_CV4))[j] = cvv;
  float4 rvv; rvv.x = 1.0f/sqrtf(s1); rvv.y = ori[j*3+0]; rvv.z = ori[j*3+1]; rvv.w = ori[j*3+2];
  ((float4*)(wsb + OFF_RV4))[j] = rvv;
}

// 3-way bf16 split of PRE-SCALED features (A x 48.09/|a|, B x 1/|b|),
// written in MFMA-fragment-packed order (see layout comment above).
__global__ void k_split(const float* __restrict__ meanf, const float* __restrict__ surf,
                        char* __restrict__ wsb) {
  const int NT = NSV*CF/4;
  int idx = blockIdx.x*256 + threadIdx.x;
  if (idx >= 2*NT) return;
  int m = idx >= NT;
  int e4 = idx - (m ? NT : 0);
  int base4 = e4 * 4;
  int row = base4 / CF;
  int k0  = base4 - row*CF;          // 0,4,...,92
  const float* src = m ? surf : meanf;
  float scale;
  if (m) scale = ((const float4*)(wsb + OFF_CV4))[row].x;
  else   scale = ((const float4*)(wsb + OFF_RV4))[row].x * C48;
  unsigned short* d0 = (unsigned short*)(wsb + (m ? OFF_B0 : OFF_A0));
  unsigned short* d1 = (unsigned short*)(wsb + (m ? OFF_B1 : OFF_A1));
  unsigned short* d2 = (unsigned short*)(wsb + (m ? OFF_B2 : OFF_A2));
  float4 v = *(const float4*)(src + base4);
  float xs[4] = {v.x*scale, v.y*scale, v.z*scale, v.w*scale};
  unsigned short h0[4], h1[4], h2[4];
  #pragma unroll
  for (int c = 0; c < 4; ++c) {
    float x = xs[c];
    unsigned short a0 = bfr(x);  float r1 = x - bff(a0);
    unsigned short a1 = bfr(r1); float r2 = r1 - bff(a1);
    h0[c] = a0; h1[c] = a1; h2[c] = bfr(r2);
  }
  // fragment-packed destination (in ushort units):
  int g   = row >> 5;
  int l31 = row & 31;
  int kc  = k0 >> 4;
  int hi  = (k0 >> 3) & 1;
  int e8  = k0 & 7;                  // 0 or 4
  int offu = ((g*6 + kc) << 9) + (((hi << 5) | l31) << 3) + e8;
  *(ushort4*)(d0 + offu) = make_ushort4(h0[0], h0[1], h0[2], h0[3]);
  *(ushort4*)(d1 + offu) = make_ushort4(h1[0], h1[1], h1[2], h1[3]);
  *(ushort4*)(d2 + offu) = make_ushort4(h2[0], h2[1], h2[2], h2[3]);
}

// Heavy GEMM pass: 128x128 tile, 4 waves (2x2), wave tile 64x64 via 2x2 mfma_32x32x16_bf16.
// Register-direct (no LDS, no barriers), fragments from L2-resident fragment-packed
// splits, register double-buffer ENFORCED via sched_group_barrier pinning:
// each k-iter emits [12 VMEM loads (kc+1)] then [24 MFMA (kc)], so the auto
// waitcnt before MFMAs is counted vmcnt(12) and next-iter loads fly under compute.
// PASS 1: rowsums.  PASS 2: per-column argmax of K*b.
template<int PASS>
__global__ __launch_bounds__(256, 2)
void k_gemm(char* __restrict__ wsb) {
  const float4* RV  = (const float4*)(wsb + OFF_RV4);
  const float4* CVC = (const float4*)(wsb + OFF_CV4);
  float* PROW = (float*)(wsb + OFF_PROW);
  unsigned long long* SME = (unsigned long long*)(wsb + OFF_SMENC);

  __shared__ unsigned long long redbuf[2][128];

  int t = threadIdx.x, lane = t & 63, wid = t >> 6;
  int wr = wid >> 1, wc = wid & 1, l31 = lane & 31, hi = lane >> 5;
  // 2D XCD chunking: XCD (xr,xc) owns 16 bi x 32 bj -> L2-resident panels
  int flat = blockIdx.y*64 + blockIdx.x;
  int xcd = flat & 7, q = flat >> 3;
  int xr = xcd >> 1, xc = xcd & 1;
  int bi = xr*16 + (q & 15), bj = xc*32 + (q >> 4);
  int I0 = bi*128, J0 = bj*128;

  // fragment base pointers: split s, sub-tile ti -> group (I0>>5) + wr*2 + ti
  const char* pA[3][2];
  const char* pB[3][2];
  {
    int gA = (I0 >> 5) + wr*2;
    int gB = (J0 >> 5) + wc*2;
    unsigned offs[3] = {OFF_A0, OFF_A1, OFF_A2};
    unsigned offsB[3] = {OFF_B0, OFF_B1, OFF_B2};
    #pragma unroll
    for (int s = 0; s < 3; ++s)
      #pragma unroll
      for (int ti = 0; ti < 2; ++ti) {
        pA[s][ti] = wsb + offs[s]  + (((gA + ti)*6) << 10) + lane*16;
        pB[s][ti] = wsb + offsB[s] + (((gB + ti)*6) << 10) + lane*16;
      }
  }

  floatx16 acc[2][2];
  #pragma unroll
  for (int ti = 0; ti < 2; ++ti)
    #pragma unroll
    for (int tj = 0; tj < 2; ++tj)
      #pragma unroll
      for (int e = 0; e < 16; ++e) acc[ti][tj][e] = 0.f;

  short8 fa[3][2], fb[3][2];
  #pragma unroll
  for (int s = 0; s < 3; ++s)
    #pragma unroll
    for (int ti = 0; ti < 2; ++ti) {
      fa[s][ti] = *(const short8*)(pA[s][ti]);
      fb[s][ti] = *(const short8*)(pB[s][ti]);
    }
  __builtin_amdgcn_sched_group_barrier(0x020, 12, 0);   // initial 12 loads first

  #pragma unroll
  for (int kc = 0; kc < 6; ++kc) {
    short8 na[3][2], nb[3][2];
    if (kc < 5) {
      #pragma unroll
      for (int s = 0; s < 3; ++s)
        #pragma unroll
        for (int ti = 0; ti < 2; ++ti) {
          na[s][ti] = *(const short8*)(pA[s][ti] + (kc+1)*1024);
          nb[s][ti] = *(const short8*)(pB[s][ti] + (kc+1)*1024);
        }
    }
    #pragma unroll
    for (int ti = 0; ti < 2; ++ti)
      #pragma unroll
      for (int tj = 0; tj < 2; ++tj) {
        acc[ti][tj] = __builtin_amdgcn_mfma_f32_32x32x16_bf16(fa[0][ti], fb[0][tj], acc[ti][tj], 0, 0, 0);
        acc[ti][tj] = __builtin_amdgcn_mfma_f32_32x32x16_bf16(fa[0][ti], fb[1][tj], acc[ti][tj], 0, 0, 0);
        acc[ti][tj] = __builtin_amdgcn_mfma_f32_32x32x16_bf16(fa[1][ti], fb[0][tj], acc[ti][tj], 0, 0, 0);
        acc[ti][tj] = __builtin_amdgcn_mfma_f32_32x32x16_bf16(fa[1][ti], fb[1][tj], acc[ti][tj], 0, 0, 0);
        acc[ti][tj] = __builtin_amdgcn_mfma_f32_32x32x16_bf16(fa[0][ti], fb[2][tj], acc[ti][tj], 0, 0, 0);
        acc[ti][tj] = __builtin_amdgcn_mfma_f32_32x32x16_bf16(fa[2][ti], fb[0][tj], acc[ti][tj], 0, 0, 0);
      }
    // pin schedule for this iteration: loads(kc+1) issue before MFMAs(kc)
    if (kc < 5) __builtin_amdgcn_sched_group_barrier(0x020, 12, 0);
    __builtin_amdgcn_sched_group_barrier(0x008, 24, 0);
    if (kc < 5) {
      #pragma unroll
      for (int s = 0; s < 3; ++s)
        #pragma unroll
        for (int ti = 0; ti < 2; ++ti) { fa[s][ti] = na[s][ti]; fb[s][ti] = nb[s][ti]; }
    }
  }

  // ---- epilogue ----
  float4 cv[2];
  #pragma unroll
  for (int tj = 0; tj < 2; ++tj) cv[tj] = CVC[J0 + wc*64 + tj*32 + l31];

  if (PASS == 1) {
    float* rowred = (float*)redbuf;   // [2][128] floats
    #pragma unroll
    for (int ti = 0; ti < 2; ++ti) {
      #pragma unroll
      for (int r = 0; r < 16; ++r) {
        int lr = wr*64 + ti*32 + (r & 3) + 8*(r >> 2) + 4*hi;
        int row = I0 + lr;
        float4 rv = RV[row];
        float rowp = 0.f;
        #pragma unroll
        for (int tj = 0; tj < 2; ++tj) {
          float dotv = acc[ti][tj][r];                  // = 48.09 * cos
          float dx = rv.y - cv[tj].y, dy = rv.z - cv[tj].z, dz = rv.w - cv[tj].w;
          float s3 = fmaf(dz, dz, fmaf(dy, dy, dx*dx));
          float ev = fexp2(s3 * CEV);                   // exp(-2*s3)
          float kv = fexp2(fmaf(ev, C48, dotv - C96));
          kv = (s3 < 25.0f) ? kv : 0.0f;
          rowp += kv;
        }
        rowp += __shfl_xor(rowp, 1);
        rowp += __shfl_xor(rowp, 2);
        rowp += __shfl_xor(rowp, 4);
        rowp += __shfl_xor(rowp, 8);
        rowp += __shfl_xor(rowp, 16);
        if (l31 == 0) rowred[wc*128 + lr] = rowp;
      }
    }
    __syncthreads();
    if (t < 128) PROW[(size_t)(I0 + t)*64 + bj] = rowred[t] + rowred[128 + t];
  } else {
    unsigned long long benc[2] = {0ull, 0ull};
    #pragma unroll
    for (int ti = 0; ti < 2; ++ti) {
      #pragma unroll
      for (int r = 0; r < 16; ++r) {
        int lr = wr*64 + ti*32 + (r & 3) + 8*(r >> 2) + 4*hi;
        int row = I0 + lr;
        float4 rv = RV[row];                            // rv.x = b_i
        unsigned rinv = 0xFFFFFFFFu - (unsigned)row;
        #pragma unroll
        for (int tj = 0; tj < 2; ++tj) {
          float dotv = acc[ti][tj][r];
          float dx = rv.y - cv[tj].y, dy = rv.z - cv[tj].z, dz = rv.w - cv[tj].w;
          float s3 = fmaf(dz, dz, fmaf(dy, dy, dx*dx));
          float ev = fexp2(s3 * CEV);
          float kv = fexp2(fmaf(ev, C48, dotv - C96));
          kv = (s3 < 25.0f) ? kv : 0.0f;
          float val = kv * rv.x;
          unsigned long long e = ((unsigned long long)__float_as_uint(val) << 32)
                               | (unsigned long long)rinv;
          benc[tj] = (e > benc[tj]) ? e : benc[tj];
        }
      }
    }
    #pragma unroll
    for (int tj = 0; tj < 2; ++tj) {
      unsigned long long o = __shfl_xor(benc[tj], 32);
      if (o > benc[tj]) benc[tj] = o;
      if (hi == 0) redbuf[wr][wc*64 + tj*32 + l31] = benc[tj];
    }
    __syncthreads();
    if (t < 128) {
      unsigned long long e0 = redbuf[0][t], e1 = redbuf[1][t];
      atomicMax(SME + (J0 + t), e0 > e1 ? e0 : e1);
    }
  }
}

// reduce partials -> b_i into RV4.x; init winner/flag/smenc
__global__ void k_bvec(char* __restrict__ wsb) {
  int i = blockIdx.x*256 + threadIdx.x;
  if (i >= NSV) return;
  const float* p = (const float*)(wsb + OFF_PROW) + (size_t)i*64;
  float s = 0.f;
  #pragma unroll
  for (int q = 0; q < 64; ++q) s += p[q];
  float b = 0x1p-13f / (s * 0x1p-13f + 1e-16f);
  ((float*)(wsb + OFF_RV4))[(size_t)i*4] = b;
  ((int*)(wsb + OFF_WIN))[i] = -1;
  ((unsigned long long*)(wsb + OFF_SMENC))[i] = 0ull;
  if (i == 0) *((int*)(wsb + OFF_FLAG)) = 0;
}

__global__ void k_softmax(const float* __restrict__ svp, float* __restrict__ out) {
  int i = blockIdx.x*256 + threadIdx.x;
  if (i >= NSV) return;
  const float* x = svp + (size_t)i*NCLS;
  float mx = x[0];
  for (int c = 1; c < NCLS; ++c) mx = fmaxf(mx, x[c]);
  float e[NCLS]; float s = 0.f;
  for (int c = 0; c < NCLS; ++c) { e[c] = expf(x[c] - mx); s += e[c]; }
  float* p = out + O_PROB + (size_t)i*NCLS;
  for (int c = 0; c < NCLS; ++c) p[c] = e[c]/s;
}

__global__ void k_conf(const int* __restrict__ gt, char* __restrict__ wsb, float* __restrict__ out) {
  int j = blockIdx.x*256 + threadIdx.x;
  if (j >= MSV) return;
  unsigned long long enc = ((const unsigned long long*)(wsb + OFF_SMENC))[j];
  int sm = (int)(0xFFFFFFFFu - (unsigned)(enc & 0xFFFFFFFFull));
  ((int*)(wsb + OFF_SMIDX))[j] = sm;
  out[O_SM + j] = (float)sm;
  float c = out[O_PROB + (size_t)sm*NCLS + gt[j]];
  ((float*)(wsb + OFF_CONF))[j] = c;
  unsigned long long m = __ballot(c > 0.1f);
  if ((threadIdx.x & 63) == 0 && m) atomicOr((int*)(wsb + OFF_FLAG), 1);
}

__global__ void k_winner(char* __restrict__ wsb) {
  int j = blockIdx.x*256 + threadIdx.x;
  if (j >= MSV) return;
  float c = ((const float*)(wsb + OFF_CONF))[j];
  int f = *((const int*)(wsb + OFF_FLAG));
  bool tm = f ? (c > 0.1f) : (c > 0.0f);
  if (tm) atomicMax(((int*)(wsb + OFF_WIN)) + ((const int*)(wsb + OFF_SMIDX))[j], j);
}

__global__ void k_final(const int* __restrict__ gt, float* __restrict__ out, const char* __restrict__ wsb) {
  int i = blockIdx.x*256 + threadIdx.x;
  if (i >= NSV) return;
  int w = ((const int*)(wsb + OFF_WIN))[i];
  float* row = out + O_PROB + (size_t)i*NCLS;
  if (w >= 0) {
    int g = gt[w];
    for (int c = 0; c < NCLS; ++c) row[c] = (c == g) ? 1.f : 0.f;
  }
  out[O_TRUST + i] = (w >= 0) ? 1.f : 0.f;
  float mx = row[0]; int pi = 0;
  for (int c = 1; c < NCLS; ++c) { float v = row[c]; if (v > mx) { mx = v; pi = c; } }
  out[O_PRE + i] = (float)pi;
}

extern "C" void kernel_launch(void* const* d_in, const int* in_sizes, int n_in,
                              void* d_out, int out_size, void* d_ws, size_t ws_size,
                              hipStream_t stream) {
  const float* surf  = (const float*)d_in[0];
  const float* surc  = (const float*)d_in[1];
  const int*   gt    = (const int*)d_in[2];
  const float* svp   = (const float*)d_in[3];
  const float* meanf = (const float*)d_in[4];
  const float* ori   = (const float*)d_in[5];
  const float* poss  = (const float*)d_in[6];
  float* out = (float*)d_out;
  char* wsb = (char*)d_ws;

  k_prep<<<NSV/256, 256, 0, stream>>>(surf, surc, meanf, ori, poss, wsb);
  k_split<<<1536, 256, 0, stream>>>(meanf, surf, wsb);
  k_gemm<1><<<dim3(64, 64), 256, 0, stream>>>(wsb);
  k_bvec<<<NSV/256, 256, 0, stream>>>(wsb);
  k_gemm<2><<<dim3(64, 64), 256, 0, stream>>>(wsb);
  k_softmax<<<NSV/256, 256, 0, stream>>>(svp, out);
  k_conf<<<MSV/256, 256, 0, stream>>>(gt, wsb, out);
  k_winner<<<MSV/256, 256, 0, stream>>>(wsb);
  k_final<<<NSV/256, 256, 0, stream>>>(gt, out, wsb);
}

// Round 11
// 300.101 us; speedup vs baseline: 1.1436x; 1.1070x over previous
//
#include <hip/hip_runtime.h>
#include <math.h>

typedef __attribute__((ext_vector_type(8))) short short8;
typedef __attribute__((ext_vector_type(16))) float floatx16;

#define NSV 8192
#define MSV 8192
#define CF 96
#define NCLS 20

#define C48 48.08983469629878f     // 1/(0.03*ln2)
#define C96 96.17966939259756f     // 2*C48
#define CEV -2.885390081777927f    // -2/ln2

// ---- workspace byte offsets ----
// A/B splits stored FRAGMENT-PACKED: within split s, byte offset
//   ((g*6 + kc) << 10) + lane*16,  g = rowgroup (32 rows), kc = k-chunk (16 k),
//   lane = (k_half<<5) | (row&31); each 16B = 8 bf16 of one row's k-half.
#define OFF_A0    0u
#define OFF_A1    1572864u
#define OFF_A2    3145728u
#define OFF_B0    4718592u
#define OFF_B1    6291456u
#define OFF_B2    7864320u
#define OFF_RV4   9437184u   // float4[8192]: x = 1/|a| (prep) then b_i (bvec); yzw = ori
#define OFF_CV4   9568256u   // float4[8192]: x = 1/|b|; yzw = al_sur
#define OFF_PROW  9699328u   // float[8192*64] partial row sums
#define OFF_SMENC 11796480u  // u64[8192]
#define OFF_SMIDX 11862016u
#define OFF_WIN   11894784u
#define OFF_CONF  11927552u
#define OFF_FLAG  11960320u

// ---- output float offsets ----
#define O_TRUST 0
#define O_PROB  NSV
#define O_PRE   (O_PROB + NSV*NCLS)
#define O_SM    (O_PRE + NSV)

__device__ __forceinline__ unsigned short bfr(float x) {
  unsigned u = __float_as_uint(x);
  return (unsigned short)((u + 0x7FFFu + ((u >> 16) & 1u)) >> 16);
}
__device__ __forceinline__ float bff(unsigned short h) {
  return __uint_as_float(((unsigned)h) << 16);
}
__device__ __forceinline__ float fexp2(float x) {
  float r; asm("v_exp_f32 %0, %1" : "=v"(r) : "v"(x)); return r;
}

// 4x4 inverse (fp64 Gauss-Jordan) + norms, coord transform, packed structs
__global__ void k_prep(const float* __restrict__ surf, const float* __restrict__ surc,
                       const float* __restrict__ meanf, const float* __restrict__ ori,
                       const float* __restrict__ posses, char* __restrict__ wsb) {
  __shared__ float dsh[12];
  if (threadIdx.x == 0) {
    double m[4][8];
    for (int r = 0; r < 4; ++r)
      for (int c = 0; c < 4; ++c) { m[r][c] = (double)posses[16 + r*4 + c]; m[r][4+c] = (r == c) ? 1.0 : 0.0; }
    for (int col = 0; col < 4; ++col) {
      int piv = col; double best = fabs(m[col][col]);
      for (int r = col+1; r < 4; ++r) { double v = fabs(m[r][col]); if (v > best) { best = v; piv = r; } }
      if (piv != col) for (int c = 0; c < 8; ++c) { double tt = m[col][c]; m[col][c] = m[piv][c]; m[piv][c] = tt; }
      double pv = m[col][col];
      for (int c = 0; c < 8; ++c) m[col][c] /= pv;
      for (int r = 0; r < 4; ++r) if (r != col) {
        double f = m[r][col];
        for (int c = 0; c < 8; ++c) m[r][c] -= f * m[col][c];
      }
    }
    for (int r = 0; r < 3; ++r)
      for (int c = 0; c < 4; ++c) {
        double s = 0.0;
        for (int k = 0; k < 4; ++k) s += m[r][4+k] * (double)posses[k*4 + c];
        dsh[r*4 + c] = (float)s;
      }
  }
  __syncthreads();
  int j = blockIdx.x*256 + threadIdx.x;
  if (j >= NSV) return;
  float d[12];
  #pragma unroll
  for (int q = 0; q < 12; ++q) d[q] = dsh[q];
  float x = surc[j*3+0], y = surc[j*3+1], z = surc[j*3+2];
  float ax = ((x*d[0] + y*d[1]) + z*d[2]) + d[3];
  float ay = ((x*d[4] + y*d[5]) + z*d[6]) + d[7];
  float az = ((x*d[8] + y*d[9]) + z*d[10]) + d[11];
  const float4* f2 = (const float4*)(surf  + (size_t)j*CF);
  const float4* f1 = (const float4*)(meanf + (size_t)j*CF);
  float s2 = 0.f, s1 = 0.f;
  #pragma unroll
  for (int kq = 0; kq < 24; ++kq) {
    float4 v = f2[kq]; s2 += v.x*v.x; s2 += v.y*v.y; s2 += v.z*v.z; s2 += v.w*v.w;
  }
  #pragma unroll
  for (int kq = 0; kq < 24; ++kq) {
    float4 v = f1[kq]; s1 += v.x*v.x; s1 += v.y*v.y; s1 += v.z*v.z; s1 += v.w*v.w;
  }
  float4 cvv; cvv.x = 1.0f/sqrtf(s2); cvv.y = ax; cvv.z = ay; cvv.w = az;
  ((float4*)(wsb + OFF_CV4))[j] = cvv;
  float4 rvv; rvv.x = 1.0f/sqrtf(s1); rvv.y = ori[j*3+0]; rvv.z = ori[j*3+1]; rvv.w = ori[j*3+2];
  ((float4*)(wsb + OFF_RV4))[j] = rvv;
}

// 3-way bf16 split of PRE-SCALED features (A x 48.09/|a|, B x 1/|b|),
// written in MFMA-fragment-packed order (see layout comment above).
__global__ void k_split(const float* __restrict__ meanf, const float* __restrict__ surf,
                        char* __restrict__ wsb) {
  const int NT = NSV*CF/4;
  int idx = blockIdx.x*256 + threadIdx.x;
  if (idx >= 2*NT) return;
  int m = idx >= NT;
  int e4 = idx - (m ? NT : 0);
  int base4 = e4 * 4;
  int row = base4 / CF;
  int k0  = base4 - row*CF;          // 0,4,...,92
  const float* src = m ? surf : meanf;
  float scale;
  if (m) scale = ((const float4*)(wsb + OFF_CV4))[row].x;
  else   scale = ((const float4*)(wsb + OFF_RV4))[row].x * C48;
  unsigned short* d0 = (unsigned short*)(wsb + (m ? OFF_B0 : OFF_A0));
  unsigned short* d1 = (unsigned short*)(wsb + (m ? OFF_B1 : OFF_A1));
  unsigned short* d2 = (unsigned short*)(wsb + (m ? OFF_B2 : OFF_A2));
  float4 v = *(const float4*)(src + base4);
  float xs[4] = {v.x*scale, v.y*scale, v.z*scale, v.w*scale};
  unsigned short h0[4], h1[4], h2[4];
  #pragma unroll
  for (int c = 0; c < 4; ++c) {
    float x = xs[c];
    unsigned short a0 = bfr(x);  float r1 = x - bff(a0);
    unsigned short a1 = bfr(r1); float r2 = r1 - bff(a1);
    h0[c] = a0; h1[c] = a1; h2[c] = bfr(r2);
  }
  // fragment-packed destination (in ushort units):
  int g   = row >> 5;
  int l31 = row & 31;
  int kc  = k0 >> 4;
  int hi  = (k0 >> 3) & 1;
  int e8  = k0 & 7;                  // 0 or 4
  int offu = ((g*6 + kc) << 9) + (((hi << 5) | l31) << 3) + e8;
  *(ushort4*)(d0 + offu) = make_ushort4(h0[0], h0[1], h0[2], h0[3]);
  *(ushort4*)(d1 + offu) = make_ushort4(h1[0], h1[1], h1[2], h1[3]);
  *(ushort4*)(d2 + offu) = make_ushort4(h2[0], h2[1], h2[2], h2[3]);
}

// Heavy GEMM pass: 128x128 tile, 4 waves (2x2), wave tile 64x64 via 2x2 mfma_32x32x16_bf16.
// Register-direct (no LDS, no barriers, NO double-buffer). Per k-step the 12 fragment
// loads are BATCH-issued before the 24 MFMAs (sched_group_barrier): L2 latency is
// exposed once per k-step instead of per-load, and ~3 co-resident waves/SIMD cover it.
// VGPR stays minimal (fa/fb live anyway) so occupancy is preserved.
// PASS 1: rowsums.  PASS 2: per-column argmax of K*b.
template<int PASS>
__global__ __launch_bounds__(256, 2)
void k_gemm(char* __restrict__ wsb) {
  const float4* RV  = (const float4*)(wsb + OFF_RV4);
  const float4* CVC = (const float4*)(wsb + OFF_CV4);
  float* PROW = (float*)(wsb + OFF_PROW);
  unsigned long long* SME = (unsigned long long*)(wsb + OFF_SMENC);

  __shared__ unsigned long long redbuf[2][128];

  int t = threadIdx.x, lane = t & 63, wid = t >> 6;
  int wr = wid >> 1, wc = wid & 1, l31 = lane & 31, hi = lane >> 5;
  // 2D XCD chunking: XCD (xr,xc) owns 16 bi x 32 bj -> L2-resident panels
  int flat = blockIdx.y*64 + blockIdx.x;
  int xcd = flat & 7, q = flat >> 3;
  int xr = xcd >> 1, xc = xcd & 1;
  int bi = xr*16 + (q & 15), bj = xc*32 + (q >> 4);
  int I0 = bi*128, J0 = bj*128;

  // fragment base pointers: split s, sub-tile ti -> group (I0>>5) + wr*2 + ti
  const char* pA[3][2];
  const char* pB[3][2];
  {
    int gA = (I0 >> 5) + wr*2;
    int gB = (J0 >> 5) + wc*2;
    unsigned offs[3] = {OFF_A0, OFF_A1, OFF_A2};
    unsigned offsB[3] = {OFF_B0, OFF_B1, OFF_B2};
    #pragma unroll
    for (int s = 0; s < 3; ++s)
      #pragma unroll
      for (int ti = 0; ti < 2; ++ti) {
        pA[s][ti] = wsb + offs[s]  + (((gA + ti)*6) << 10) + lane*16;
        pB[s][ti] = wsb + offsB[s] + (((gB + ti)*6) << 10) + lane*16;
      }
  }

  floatx16 acc[2][2];
  #pragma unroll
  for (int ti = 0; ti < 2; ++ti)
    #pragma unroll
    for (int tj = 0; tj < 2; ++tj)
      #pragma unroll
      for (int e = 0; e < 16; ++e) acc[ti][tj][e] = 0.f;

  #pragma unroll
  for (int kc = 0; kc < 6; ++kc) {
    short8 fa[3][2], fb[3][2];
    #pragma unroll
    for (int s = 0; s < 3; ++s)
      #pragma unroll
      for (int ti = 0; ti < 2; ++ti) {
        fa[s][ti] = *(const short8*)(pA[s][ti] + kc*1024);
        fb[s][ti] = *(const short8*)(pB[s][ti] + kc*1024);
      }
    #pragma unroll
    for (int ti = 0; ti < 2; ++ti)
      #pragma unroll
      for (int tj = 0; tj < 2; ++tj) {
        acc[ti][tj] = __builtin_amdgcn_mfma_f32_32x32x16_bf16(fa[0][ti], fb[0][tj], acc[ti][tj], 0, 0, 0);
        acc[ti][tj] = __builtin_amdgcn_mfma_f32_32x32x16_bf16(fa[0][ti], fb[1][tj], acc[ti][tj], 0, 0, 0);
        acc[ti][tj] = __builtin_amdgcn_mfma_f32_32x32x16_bf16(fa[1][ti], fb[0][tj], acc[ti][tj], 0, 0, 0);
        acc[ti][tj] = __builtin_amdgcn_mfma_f32_32x32x16_bf16(fa[1][ti], fb[1][tj], acc[ti][tj], 0, 0, 0);
        acc[ti][tj] = __builtin_amdgcn_mfma_f32_32x32x16_bf16(fa[0][ti], fb[2][tj], acc[ti][tj], 0, 0, 0);
        acc[ti][tj] = __builtin_amdgcn_mfma_f32_32x32x16_bf16(fa[2][ti], fb[0][tj], acc[ti][tj], 0, 0, 0);
      }
    // pin: this k-step's 12 loads issue as a batch BEFORE its 24 MFMAs
    __builtin_amdgcn_sched_group_barrier(0x020, 12, 0);  // VMEM_READ
    __builtin_amdgcn_sched_group_barrier(0x008, 24, 0);  // MFMA
  }

  // ---- epilogue ----
  float4 cv[2];
  #pragma unroll
  for (int tj = 0; tj < 2; ++tj) cv[tj] = CVC[J0 + wc*64 + tj*32 + l31];

  if (PASS == 1) {
    float* rowred = (float*)redbuf;   // [2][128] floats
    #pragma unroll
    for (int ti = 0; ti < 2; ++ti) {
      #pragma unroll
      for (int r = 0; r < 16; ++r) {
        int lr = wr*64 + ti*32 + (r & 3) + 8*(r >> 2) + 4*hi;
        int row = I0 + lr;
        float4 rv = RV[row];
        float rowp = 0.f;
        #pragma unroll
        for (int tj = 0; tj < 2; ++tj) {
          float dotv = acc[ti][tj][r];                  // = 48.09 * cos
          float dx = rv.y - cv[tj].y, dy = rv.z - cv[tj].z, dz = rv.w - cv[tj].w;
          float s3 = fmaf(dz, dz, fmaf(dy, dy, dx*dx));
          float ev = fexp2(s3 * CEV);                   // exp(-2*s3)
          float kv = fexp2(fmaf(ev, C48, dotv - C96));
          kv = (s3 < 25.0f) ? kv : 0.0f;
          rowp += kv;
        }
        rowp += __shfl_xor(rowp, 1);
        rowp += __shfl_xor(rowp, 2);
        rowp += __shfl_xor(rowp, 4);
        rowp += __shfl_xor(rowp, 8);
        rowp += __shfl_xor(rowp, 16);
        if (l31 == 0) rowred[wc*128 + lr] = rowp;
      }
    }
    __syncthreads();
    if (t < 128) PROW[(size_t)(I0 + t)*64 + bj] = rowred[t] + rowred[128 + t];
  } else {
    unsigned long long benc[2] = {0ull, 0ull};
    #pragma unroll
    for (int ti = 0; ti < 2; ++ti) {
      #pragma unroll
      for (int r = 0; r < 16; ++r) {
        int lr = wr*64 + ti*32 + (r & 3) + 8*(r >> 2) + 4*hi;
        int row = I0 + lr;
        float4 rv = RV[row];                            // rv.x = b_i
        unsigned rinv = 0xFFFFFFFFu - (unsigned)row;
        #pragma unroll
        for (int tj = 0; tj < 2; ++tj) {
          float dotv = acc[ti][tj][r];
          float dx = rv.y - cv[tj].y, dy = rv.z - cv[tj].z, dz = rv.w - cv[tj].w;
          float s3 = fmaf(dz, dz, fmaf(dy, dy, dx*dx));
          float ev = fexp2(s3 * CEV);
          float kv = fexp2(fmaf(ev, C48, dotv - C96));
          kv = (s3 < 25.0f) ? kv : 0.0f;
          float val = kv * rv.x;
          unsigned long long e = ((unsigned long long)__float_as_uint(val) << 32)
                               | (unsigned long long)rinv;
          benc[tj] = (e > benc[tj]) ? e : benc[tj];
        }
      }
    }
    #pragma unroll
    for (int tj = 0; tj < 2; ++tj) {
      unsigned long long o = __shfl_xor(benc[tj], 32);
      if (o > benc[tj]) benc[tj] = o;
      if (hi == 0) redbuf[wr][wc*64 + tj*32 + l31] = benc[tj];
    }
    __syncthreads();
    if (t < 128) {
      unsigned long long e0 = redbuf[0][t], e1 = redbuf[1][t];
      atomicMax(SME + (J0 + t), e0 > e1 ? e0 : e1);
    }
  }
}

// reduce partials -> b_i into RV4.x; init winner/flag/smenc
__global__ void k_bvec(char* __restrict__ wsb) {
  int i = blockIdx.x*256 + threadIdx.x;
  if (i >= NSV) return;
  const float* p = (const float*)(wsb + OFF_PROW) + (size_t)i*64;
  float s = 0.f;
  #pragma unroll
  for (int q = 0; q < 64; ++q) s += p[q];
  float b = 0x1p-13f / (s * 0x1p-13f + 1e-16f);
  ((float*)(wsb + OFF_RV4))[(size_t)i*4] = b;
  ((int*)(wsb + OFF_WIN))[i] = -1;
  ((unsigned long long*)(wsb + OFF_SMENC))[i] = 0ull;
  if (i == 0) *((int*)(wsb + OFF_FLAG)) = 0;
}

__global__ void k_softmax(const float* __restrict__ svp, float* __restrict__ out) {
  int i = blockIdx.x*256 + threadIdx.x;
  if (i >= NSV) return;
  const float* x = svp + (size_t)i*NCLS;
  float mx = x[0];
  for (int c = 1; c < NCLS; ++c) mx = fmaxf(mx, x[c]);
  float e[NCLS]; float s = 0.f;
  for (int c = 0; c < NCLS; ++c) { e[c] = expf(x[c] - mx); s += e[c]; }
  float* p = out + O_PROB + (size_t)i*NCLS;
  for (int c = 0; c < NCLS; ++c) p[c] = e[c]/s;
}

__global__ void k_conf(const int* __restrict__ gt, char* __restrict__ wsb, float* __restrict__ out) {
  int j = blockIdx.x*256 + threadIdx.x;
  if (j >= MSV) return;
  unsigned long long enc = ((const unsigned long long*)(wsb + OFF_SMENC))[j];
  int sm = (int)(0xFFFFFFFFu - (unsigned)(enc & 0xFFFFFFFFull));
  ((int*)(wsb + OFF_SMIDX))[j] = sm;
  out[O_SM + j] = (float)sm;
  float c = out[O_PROB + (size_t)sm*NCLS + gt[j]];
  ((float*)(wsb + OFF_CONF))[j] = c;
  unsigned long long m = __ballot(c > 0.1f);
  if ((threadIdx.x & 63) == 0 && m) atomicOr((int*)(wsb + OFF_FLAG), 1);
}

__global__ void k_winner(char* __restrict__ wsb) {
  int j = blockIdx.x*256 + threadIdx.x;
  if (j >= MSV) return;
  float c = ((const float*)(wsb + OFF_CONF))[j];
  int f = *((const int*)(wsb + OFF_FLAG));
  bool tm = f ? (c > 0.1f) : (c > 0.0f);
  if (tm) atomicMax(((int*)(wsb + OFF_WIN)) + ((const int*)(wsb + OFF_SMIDX))[j], j);
}

__global__ void k_final(const int* __restrict__ gt, float* __restrict__ out, const char* __restrict__ wsb) {
  int i = blockIdx.x*256 + threadIdx.x;
  if (i >= NSV) return;
  int w = ((const int*)(wsb + OFF_WIN))[i];
  float* row = out + O_PROB + (size_t)i*NCLS;
  if (w >= 0) {
    int g = gt[w];
    for (int c = 0; c < NCLS; ++c) row[c] = (c == g) ? 1.f : 0.f;
  }
  out[O_TRUST + i] = (w >= 0) ? 1.f : 0.f;
  float mx = row[0]; int pi = 0;
  for (int c = 1; c < NCLS; ++c) { float v = row[c]; if (v > mx) { mx = v; pi = c; } }
  out[O_PRE + i] = (float)pi;
}

extern "C" void kernel_launch(void* const* d_in, const int* in_sizes, int n_in,
                              void* d_out, int out_size, void* d_ws, size_t ws_size,
                              hipStream_t stream) {
  const float* surf  = (const float*)d_in[0];
  const float* surc  = (const float*)d_in[1];
  const int*   gt    = (const int*)d_in[2];
  const float* svp   = (const float*)d_in[3];
  const float* meanf = (const float*)d_in[4];
  const float* ori   = (const float*)d_in[5];
  const float* poss  = (const float*)d_in[6];
  float* out = (float*)d_out;
  char* wsb = (char*)d_ws;

  k_prep<<<NSV/256, 256, 0, stream>>>(surf, surc, meanf, ori, poss, wsb);
  k_split<<<1536, 256, 0, stream>>>(meanf, surf, wsb);
  k_gemm<1><<<dim3(64, 64), 256, 0, stream>>>(wsb);
  k_bvec<<<NSV/256, 256, 0, stream>>>(wsb);
  k_gemm<2><<<dim3(64, 64), 256, 0, stream>>>(wsb);
  k_softmax<<<NSV/256, 256, 0, stream>>>(svp, out);
  k_conf<<<MSV/256, 256, 0, stream>>>(gt, wsb, out);
  k_winner<<<MSV/256, 256, 0, stream>>>(wsb);
  k_final<<<NSV/256, 256, 0, stream>>>(gt, out, wsb);
}

// Round 12
// 292.591 us; speedup vs baseline: 1.1730x; 1.0257x over previous
//
#include <hip/hip_runtime.h>
#include <math.h>

typedef __attribute__((ext_vector_type(8))) short short8;
typedef __attribute__((ext_vector_type(16))) float floatx16;

#define NSV 8192
#define MSV 8192
#define CF 96
#define NCLS 20

#define C48 48.08983469629878f     // 1/(0.03*ln2)
#define C96 96.17966939259756f     // 2*C48
#define CEV -2.885390081777927f    // -2/ln2

// ---- workspace byte offsets ----
// A/B splits stored FRAGMENT-PACKED: within split s, byte offset
//   ((g*6 + kc) << 10) + lane*16,  g = rowgroup (32 rows), kc = k-chunk (16 k),
//   lane = (k_half<<5) | (row&31); each 16B = 8 bf16 of one row's k-half.
#define OFF_A0    0u
#define OFF_A1    1572864u
#define OFF_A2    3145728u
#define OFF_B0    4718592u
#define OFF_B1    6291456u
#define OFF_B2    7864320u
#define OFF_RV4   9437184u   // float4[8192]: x = 1/|a| (prep) then b_i (bvec); yzw = ori
#define OFF_CV4   9568256u   // float4[8192]: x = 1/|b|; yzw = al_sur
#define OFF_PROW  9699328u   // float[8192*64] partial row sums
#define OFF_SMENC 11796480u  // u64[8192]
#define OFF_SMIDX 11862016u
#define OFF_WIN   11894784u
#define OFF_CONF  11927552u
#define OFF_FLAG  11960320u

// ---- output float offsets ----
#define O_TRUST 0
#define O_PROB  NSV
#define O_PRE   (O_PROB + NSV*NCLS)
#define O_SM    (O_PRE + NSV)

__device__ __forceinline__ unsigned short bfr(float x) {
  unsigned u = __float_as_uint(x);
  return (unsigned short)((u + 0x7FFFu + ((u >> 16) & 1u)) >> 16);
}
__device__ __forceinline__ float bff(unsigned short h) {
  return __uint_as_float(((unsigned)h) << 16);
}
__device__ __forceinline__ float fexp2(float x) {
  float r; asm("v_exp_f32 %0, %1" : "=v"(r) : "v"(x)); return r;
}

// Fused prep+split: static cofactor fp64 inverse (no scratch), norms, coord
// transform, and 3-way bf16 split of PRE-SCALED features written in
// MFMA-fragment-packed order. One thread per matrix row (A rows then B rows).
__global__ __launch_bounds__(256)
void k_prep(const float* __restrict__ surf, const float* __restrict__ surc,
            const float* __restrict__ meanf, const float* __restrict__ ori,
            const float* __restrict__ posses, char* __restrict__ wsb) {
  __shared__ float dsh[12];
  if (threadIdx.x == 0) {
    // diff = inv(P1) @ P0, rows 0..2 — static cofactor method (registers only)
    const float* P1 = posses + 16;
    const float* P0 = posses;
    double a00=P1[0],  a01=P1[1],  a02=P1[2],  a03=P1[3];
    double a10=P1[4],  a11=P1[5],  a12=P1[6],  a13=P1[7];
    double a20=P1[8],  a21=P1[9],  a22=P1[10], a23=P1[11];
    double a30=P1[12], a31=P1[13], a32=P1[14], a33=P1[15];
    double s0 = a00*a11 - a01*a10;
    double s1 = a00*a12 - a02*a10;
    double s2 = a00*a13 - a03*a10;
    double s3 = a01*a12 - a02*a11;
    double s4 = a01*a13 - a03*a11;
    double s5 = a02*a13 - a03*a12;
    double c5 = a22*a33 - a23*a32;
    double c4 = a21*a33 - a23*a31;
    double c3 = a21*a32 - a22*a31;
    double c2 = a20*a33 - a23*a30;
    double c1 = a20*a32 - a22*a30;
    double c0 = a20*a31 - a21*a30;
    double det = s0*c5 - s1*c4 + s2*c3 + s3*c2 - s4*c1 + s5*c0;
    double id = 1.0/det;
    double inv[3][4];
    inv[0][0] = ( a11*c5 - a12*c4 + a13*c3) * id;
    inv[0][1] = (-a01*c5 + a02*c4 - a03*c3) * id;
    inv[0][2] = ( a31*s5 - a32*s4 + a33*s3) * id;
    inv[0][3] = (-a21*s5 + a22*s4 - a23*s3) * id;
    inv[1][0] = (-a10*c5 + a12*c2 - a13*c1) * id;
    inv[1][1] = ( a00*c5 - a02*c2 + a03*c1) * id;
    inv[1][2] = (-a30*s5 + a32*s2 - a33*s1) * id;
    inv[1][3] = ( a20*s5 - a22*s2 + a23*s1) * id;
    inv[2][0] = ( a10*c4 - a11*c2 + a13*c0) * id;
    inv[2][1] = (-a00*c4 + a01*c2 - a03*c0) * id;
    inv[2][2] = ( a30*s4 - a31*s2 + a33*s0) * id;
    inv[2][3] = (-a20*s4 + a21*s2 - a23*s0) * id;
    #pragma unroll
    for (int r = 0; r < 3; ++r)
      #pragma unroll
      for (int c = 0; c < 4; ++c) {
        double s = 0.0;
        #pragma unroll
        for (int k = 0; k < 4; ++k) s += inv[r][k] * (double)P0[k*4 + c];
        dsh[r*4 + c] = (float)s;
      }
  }
  __syncthreads();

  int idx = blockIdx.x*256 + threadIdx.x;
  if (idx >= 2*NSV) return;
  int m = idx >= NSV;
  int j = idx - (m ? NSV : 0);
  const float* src = m ? surf : meanf;
  const float4* fr = (const float4*)(src + (size_t)j*CF);

  float4 v[24];
  #pragma unroll
  for (int kq = 0; kq < 24; ++kq) v[kq] = fr[kq];
  float s = 0.f;
  #pragma unroll
  for (int kq = 0; kq < 24; ++kq) {
    s += v[kq].x*v[kq].x; s += v[kq].y*v[kq].y; s += v[kq].z*v[kq].z; s += v[kq].w*v[kq].w;
  }
  float rn = 1.0f/sqrtf(s);                       // same expr as before
  float scale;
  if (m) {
    // B side: coord transform + CV4
    float d[12];
    #pragma unroll
    for (int q = 0; q < 12; ++q) d[q] = dsh[q];
    float x = surc[j*3+0], y = surc[j*3+1], z = surc[j*3+2];
    float ax = ((x*d[0] + y*d[1]) + z*d[2]) + d[3];
    float ay = ((x*d[4] + y*d[5]) + z*d[6]) + d[7];
    float az = ((x*d[8] + y*d[9]) + z*d[10]) + d[11];
    float4 cvv; cvv.x = rn; cvv.y = ax; cvv.z = ay; cvv.w = az;
    ((float4*)(wsb + OFF_CV4))[j] = cvv;
    scale = rn;                                   // == cvv.x (bit-identical to old k_split)
  } else {
    float4 rvv; rvv.x = rn; rvv.y = ori[j*3+0]; rvv.z = ori[j*3+1]; rvv.w = ori[j*3+2];
    ((float4*)(wsb + OFF_RV4))[j] = rvv;
    scale = rn * C48;                             // == rvv.x * C48 (bit-identical)
  }

  unsigned short* d0 = (unsigned short*)(wsb + (m ? OFF_B0 : OFF_A0));
  unsigned short* d1 = (unsigned short*)(wsb + (m ? OFF_B1 : OFF_A1));
  unsigned short* d2 = (unsigned short*)(wsb + (m ? OFF_B2 : OFF_A2));
  int g = j >> 5, l31 = j & 31;
  #pragma unroll
  for (int kq = 0; kq < 24; ++kq) {
    int k0 = kq*4;
    float xs[4] = {v[kq].x*scale, v[kq].y*scale, v[kq].z*scale, v[kq].w*scale};
    unsigned short h0[4], h1[4], h2[4];
    #pragma unroll
    for (int c = 0; c < 4; ++c) {
      float x = xs[c];
      unsigned short a0 = bfr(x);  float r1 = x - bff(a0);
      unsigned short a1 = bfr(r1); float r2 = r1 - bff(a1);
      h0[c] = a0; h1[c] = a1; h2[c] = bfr(r2);
    }
    int kc = k0 >> 4;
    int hi = (k0 >> 3) & 1;
    int e8 = k0 & 7;
    int offu = ((g*6 + kc) << 9) + (((hi << 5) | l31) << 3) + e8;
    *(ushort4*)(d0 + offu) = make_ushort4(h0[0], h0[1], h0[2], h0[3]);
    *(ushort4*)(d1 + offu) = make_ushort4(h1[0], h1[1], h1[2], h1[3]);
    *(ushort4*)(d2 + offu) = make_ushort4(h2[0], h2[1], h2[2], h2[3]);
  }
}

// Heavy GEMM pass (round-8 config): 128x128 tile, 4 waves (2x2), wave tile 64x64
// via 2x2 mfma_32x32x16_bf16. Register-direct from L2-resident fragment-packed
// splits (fully coalesced 64x16B loads), no LDS, no main-loop barriers.
// PASS 1: rowsums.  PASS 2: per-column argmax of K*b.
template<int PASS>
__global__ __launch_bounds__(256, 2)
void k_gemm(char* __restrict__ wsb) {
  const float4* RV  = (const float4*)(wsb + OFF_RV4);
  const float4* CVC = (const float4*)(wsb + OFF_CV4);
  float* PROW = (float*)(wsb + OFF_PROW);
  unsigned long long* SME = (unsigned long long*)(wsb + OFF_SMENC);

  __shared__ unsigned long long redbuf[2][128];

  int t = threadIdx.x, lane = t & 63, wid = t >> 6;
  int wr = wid >> 1, wc = wid & 1, l31 = lane & 31, hi = lane >> 5;
  // 2D XCD chunking: XCD (xr,xc) owns 16 bi x 32 bj -> L2-resident panels
  int flat = blockIdx.y*64 + blockIdx.x;
  int xcd = flat & 7, q = flat >> 3;
  int xr = xcd >> 1, xc = xcd & 1;
  int bi = xr*16 + (q & 15), bj = xc*32 + (q >> 4);
  int I0 = bi*128, J0 = bj*128;

  const char* pA[3][2];
  const char* pB[3][2];
  {
    int gA = (I0 >> 5) + wr*2;
    int gB = (J0 >> 5) + wc*2;
    unsigned offs[3] = {OFF_A0, OFF_A1, OFF_A2};
    unsigned offsB[3] = {OFF_B0, OFF_B1, OFF_B2};
    #pragma unroll
    for (int s = 0; s < 3; ++s)
      #pragma unroll
      for (int ti = 0; ti < 2; ++ti) {
        pA[s][ti] = wsb + offs[s]  + (((gA + ti)*6) << 10) + lane*16;
        pB[s][ti] = wsb + offsB[s] + (((gB + ti)*6) << 10) + lane*16;
      }
  }

  floatx16 acc[2][2];
  #pragma unroll
  for (int ti = 0; ti < 2; ++ti)
    #pragma unroll
    for (int tj = 0; tj < 2; ++tj)
      #pragma unroll
      for (int e = 0; e < 16; ++e) acc[ti][tj][e] = 0.f;

  short8 fa[3][2], fb[3][2];
  #pragma unroll
  for (int s = 0; s < 3; ++s)
    #pragma unroll
    for (int ti = 0; ti < 2; ++ti) {
      fa[s][ti] = *(const short8*)(pA[s][ti]);
      fb[s][ti] = *(const short8*)(pB[s][ti]);
    }

  #pragma unroll
  for (int kc = 0; kc < 6; ++kc) {
    short8 na[3][2], nb[3][2];
    if (kc < 5) {
      #pragma unroll
      for (int s = 0; s < 3; ++s)
        #pragma unroll
        for (int ti = 0; ti < 2; ++ti) {
          na[s][ti] = *(const short8*)(pA[s][ti] + (kc+1)*1024);
          nb[s][ti] = *(const short8*)(pB[s][ti] + (kc+1)*1024);
        }
    }
    #pragma unroll
    for (int ti = 0; ti < 2; ++ti)
      #pragma unroll
      for (int tj = 0; tj < 2; ++tj) {
        acc[ti][tj] = __builtin_amdgcn_mfma_f32_32x32x16_bf16(fa[0][ti], fb[0][tj], acc[ti][tj], 0, 0, 0);
        acc[ti][tj] = __builtin_amdgcn_mfma_f32_32x32x16_bf16(fa[0][ti], fb[1][tj], acc[ti][tj], 0, 0, 0);
        acc[ti][tj] = __builtin_amdgcn_mfma_f32_32x32x16_bf16(fa[1][ti], fb[0][tj], acc[ti][tj], 0, 0, 0);
        acc[ti][tj] = __builtin_amdgcn_mfma_f32_32x32x16_bf16(fa[1][ti], fb[1][tj], acc[ti][tj], 0, 0, 0);
        acc[ti][tj] = __builtin_amdgcn_mfma_f32_32x32x16_bf16(fa[0][ti], fb[2][tj], acc[ti][tj], 0, 0, 0);
        acc[ti][tj] = __builtin_amdgcn_mfma_f32_32x32x16_bf16(fa[2][ti], fb[0][tj], acc[ti][tj], 0, 0, 0);
      }
    if (kc < 5) {
      #pragma unroll
      for (int s = 0; s < 3; ++s)
        #pragma unroll
        for (int ti = 0; ti < 2; ++ti) { fa[s][ti] = na[s][ti]; fb[s][ti] = nb[s][ti]; }
    }
  }

  // ---- epilogue ----
  float4 cv[2];
  #pragma unroll
  for (int tj = 0; tj < 2; ++tj) cv[tj] = CVC[J0 + wc*64 + tj*32 + l31];

  if (PASS == 1) {
    float* rowred = (float*)redbuf;   // [2][128] floats
    #pragma unroll
    for (int ti = 0; ti < 2; ++ti) {
      #pragma unroll
      for (int r = 0; r < 16; ++r) {
        int lr = wr*64 + ti*32 + (r & 3) + 8*(r >> 2) + 4*hi;
        int row = I0 + lr;
        float4 rv = RV[row];
        float rowp = 0.f;
        #pragma unroll
        for (int tj = 0; tj < 2; ++tj) {
          float dotv = acc[ti][tj][r];                  // = 48.09 * cos
          float dx = rv.y - cv[tj].y, dy = rv.z - cv[tj].z, dz = rv.w - cv[tj].w;
          float s3 = fmaf(dz, dz, fmaf(dy, dy, dx*dx));
          float ev = fexp2(s3 * CEV);                   // exp(-2*s3)
          float kv = fexp2(fmaf(ev, C48, dotv - C96));
          kv = (s3 < 25.0f) ? kv : 0.0f;
          rowp += kv;
        }
        rowp += __shfl_xor(rowp, 1);
        rowp += __shfl_xor(rowp, 2);
        rowp += __shfl_xor(rowp, 4);
        rowp += __shfl_xor(rowp, 8);
        rowp += __shfl_xor(rowp, 16);
        if (l31 == 0) rowred[wc*128 + lr] = rowp;
      }
    }
    __syncthreads();
    if (t < 128) PROW[(size_t)(I0 + t)*64 + bj] = rowred[t] + rowred[128 + t];
  } else {
    unsigned long long benc[2] = {0ull, 0ull};
    #pragma unroll
    for (int ti = 0; ti < 2; ++ti) {
      #pragma unroll
      for (int r = 0; r < 16; ++r) {
        int lr = wr*64 + ti*32 + (r & 3) + 8*(r >> 2) + 4*hi;
        int row = I0 + lr;
        float4 rv = RV[row];                            // rv.x = b_i
        unsigned rinv = 0xFFFFFFFFu - (unsigned)row;
        #pragma unroll
        for (int tj = 0; tj < 2; ++tj) {
          float dotv = acc[ti][tj][r];
          float dx = rv.y - cv[tj].y, dy = rv.z - cv[tj].z, dz = rv.w - cv[tj].w;
          float s3 = fmaf(dz, dz, fmaf(dy, dy, dx*dx));
          float ev = fexp2(s3 * CEV);
          float kv = fexp2(fmaf(ev, C48, dotv - C96));
          kv = (s3 < 25.0f) ? kv : 0.0f;
          float val = kv * rv.x;
          unsigned long long e = ((unsigned long long)__float_as_uint(val) << 32)
                               | (unsigned long long)rinv;
          benc[tj] = (e > benc[tj]) ? e : benc[tj];
        }
      }
    }
    #pragma unroll
    for (int tj = 0; tj < 2; ++tj) {
      unsigned long long o = __shfl_xor(benc[tj], 32);
      if (o > benc[tj]) benc[tj] = o;
      if (hi == 0) redbuf[wr][wc*64 + tj*32 + l31] = benc[tj];
    }
    __syncthreads();
    if (t < 128) {
      unsigned long long e0 = redbuf[0][t], e1 = redbuf[1][t];
      atomicMax(SME + (J0 + t), e0 > e1 ? e0 : e1);
    }
  }
}

// reduce partials -> b_i into RV4.x; init winner/flag/smenc
__global__ void k_bvec(char* __restrict__ wsb) {
  int i = blockIdx.x*256 + threadIdx.x;
  if (i >= NSV) return;
  const float* p = (const float*)(wsb + OFF_PROW) + (size_t)i*64;
  float s = 0.f;
  #pragma unroll
  for (int q = 0; q < 64; ++q) s += p[q];
  float b = 0x1p-13f / (s * 0x1p-13f + 1e-16f);
  ((float*)(wsb + OFF_RV4))[(size_t)i*4] = b;
  ((int*)(wsb + OFF_WIN))[i] = -1;
  ((unsigned long long*)(wsb + OFF_SMENC))[i] = 0ull;
  if (i == 0) *((int*)(wsb + OFF_FLAG)) = 0;
}

__global__ void k_softmax(const float* __restrict__ svp, float* __restrict__ out) {
  int i = blockIdx.x*256 + threadIdx.x;
  if (i >= NSV) return;
  const float* x = svp + (size_t)i*NCLS;
  float mx = x[0];
  for (int c = 1; c < NCLS; ++c) mx = fmaxf(mx, x[c]);
  float e[NCLS]; float s = 0.f;
  for (int c = 0; c < NCLS; ++c) { e[c] = expf(x[c] - mx); s += e[c]; }
  float* p = out + O_PROB + (size_t)i*NCLS;
  for (int c = 0; c < NCLS; ++c) p[c] = e[c]/s;
}

__global__ void k_conf(const int* __restrict__ gt, char* __restrict__ wsb, float* __restrict__ out) {
  int j = blockIdx.x*256 + threadIdx.x;
  if (j >= MSV) return;
  unsigned long long enc = ((const unsigned long long*)(wsb + OFF_SMENC))[j];
  int sm = (int)(0xFFFFFFFFu - (unsigned)(enc & 0xFFFFFFFFull));
  ((int*)(wsb + OFF_SMIDX))[j] = sm;
  out[O_SM + j] = (float)sm;
  float c = out[O_PROB + (size_t)sm*NCLS + gt[j]];
  ((float*)(wsb + OFF_CONF))[j] = c;
  unsigned long long m = __ballot(c > 0.1f);
  if ((threadIdx.x & 63) == 0 && m) atomicOr((int*)(wsb + OFF_FLAG), 1);
}

__global__ void k_winner(char* __restrict__ wsb) {
  int j = blockIdx.x*256 + threadIdx.x;
  if (j >= MSV) return;
  float c = ((const float*)(wsb + OFF_CONF))[j];
  int f = *((const int*)(wsb + OFF_FLAG));
  bool tm = f ? (c > 0.1f) : (c > 0.0f);
  if (tm) atomicMax(((int*)(wsb + OFF_WIN)) + ((const int*)(wsb + OFF_SMIDX))[j], j);
}

__global__ void k_final(const int* __restrict__ gt, float* __restrict__ out, const char* __restrict__ wsb) {
  int i = blockIdx.x*256 + threadIdx.x;
  if (i >= NSV) return;
  int w = ((const int*)(wsb + OFF_WIN))[i];
  float* row = out + O_PROB + (size_t)i*NCLS;
  if (w >= 0) {
    int g = gt[w];
    for (int c = 0; c < NCLS; ++c) row[c] = (c == g) ? 1.f : 0.f;
  }
  out[O_TRUST + i] = (w >= 0) ? 1.f : 0.f;
  float mx = row[0]; int pi = 0;
  for (int c = 1; c < NCLS; ++c) { float v = row[c]; if (v > mx) { mx = v; pi = c; } }
  out[O_PRE + i] = (float)pi;
}

extern "C" void kernel_launch(void* const* d_in, const int* in_sizes, int n_in,
                              void* d_out, int out_size, void* d_ws, size_t ws_size,
                              hipStream_t stream) {
  const float* surf  = (const float*)d_in[0];
  const float* surc  = (const float*)d_in[1];
  const int*   gt    = (const int*)d_in[2];
  const float* svp   = (const float*)d_in[3];
  const float* meanf = (const float*)d_in[4];
  const float* ori   = (const float*)d_in[5];
  const float* poss  = (const float*)d_in[6];
  float* out = (float*)d_out;
  char* wsb = (char*)d_ws;

  k_prep<<<2*NSV/256, 256, 0, stream>>>(surf, surc, meanf, ori, poss, wsb);
  k_gemm<1><<<dim3(64, 64), 256, 0, stream>>>(wsb);
  k_bvec<<<NSV/256, 256, 0, stream>>>(wsb);
  k_gemm<2><<<dim3(64, 64), 256, 0, stream>>>(wsb);
  k_softmax<<<NSV/256, 256, 0, stream>>>(svp, out);
  k_conf<<<MSV/256, 256, 0, stream>>>(gt, wsb, out);
  k_winner<<<MSV/256, 256, 0, stream>>>(wsb);
  k_final<<<NSV/256, 256, 0, stream>>>(gt, out, wsb);
}